// Round 7
// baseline (287.806 us; speedup 1.0000x reference)
//
#include <hip/hip_runtime.h>
#include <hip/hip_bf16.h>

// Problem constants: B=2, T=2048, C=1024, H=16, D=64
#define B_ 2
#define T_ 2048
#define C_ 1024
#define H_ 16
#define D_ 64
#define M_ 4096
#define N3C 3072

using short8  = __attribute__((ext_vector_type(8))) short;
using floatx4 = __attribute__((ext_vector_type(4))) float;
typedef unsigned int u32;

__device__ __forceinline__ unsigned short f2b(float f) {
  __hip_bfloat16 h = __float2bfloat16(f);
  return *reinterpret_cast<unsigned short*>(&h);
}
__device__ __forceinline__ float b2f(unsigned short u) {
  union { unsigned int i; float f; } x; x.i = ((unsigned int)u) << 16; return x.f;
}
__device__ __forceinline__ u32 pk2(float a, float b) {   // packed bf16x2
  float2 t; t.x = a; t.y = b;
  __hip_bfloat162 p = __float22bfloat162_rn(t);
  return *reinterpret_cast<u32*>(&p);
}

// async global->LDS, 16B per lane; LDS dest = wave-uniform base + lane*16
__device__ __forceinline__ void gll16(const void* g, void* l) {
  __builtin_amdgcn_global_load_lds((const __attribute__((address_space(1))) u32*)g,
                                   (__attribute__((address_space(3))) u32*)l, 16, 0, 0);
}

// counted-vmcnt barrier: wait until at most N vmem ops outstanding, then
// block-barrier. asm memory clobbers sandwich the barrier so the compiler
// cannot hoist/sink LDS accesses across it.
#define SYNCV(N) do {                                                   \
    asm volatile("s_waitcnt vmcnt(" #N ")" ::: "memory");               \
    __builtin_amdgcn_s_barrier();                                       \
    asm volatile("" ::: "memory");                                      \
  } while (0)

// ---------------- ternarization ----------------

// both tensors in one launch; per-block LDS reduce -> 1 atomic/block
__global__ void abs_sum2(const float* __restrict__ wq, const float* __restrict__ wp,
                         double* __restrict__ sums) {
  __shared__ double red[4];
  const float* w = blockIdx.y ? wp : wq;
  const int n4 = blockIdx.y ? (C_ * C_ / 4) : (3 * C_ * C_ / 4);
  int stride = gridDim.x * blockDim.x;
  double s = 0.0;
  for (int i = blockIdx.x * blockDim.x + threadIdx.x; i < n4; i += stride) {
    float4 v = ((const float4*)w)[i];
    s += (double)fabsf(v.x) + (double)fabsf(v.y) + (double)fabsf(v.z) + (double)fabsf(v.w);
  }
  #pragma unroll
  for (int off = 32; off > 0; off >>= 1)
    s += __shfl_down(s, off, 64);
  if ((threadIdx.x & 63) == 0) red[threadIdx.x >> 6] = s;
  __syncthreads();
  if (threadIdx.x == 0) atomicAdd(sums + blockIdx.y, (red[0] + red[1]) + (red[2] + red[3]));
}

// ternarize both weight tensors (exact {-1,0,+1} bf16) + cvt x->bf16, one launch
__global__ void tern_cvt(const float* __restrict__ wq, const float* __restrict__ wp,
                         const float* __restrict__ x,
                         unsigned short* __restrict__ oq, unsigned short* __restrict__ op,
                         unsigned short* __restrict__ xb,
                         const double* __restrict__ sums, float* __restrict__ ams) {
  const int NQ = 3 * C_ * C_;
  const int NP = C_ * C_;
  int i = blockIdx.x * blockDim.x + threadIdx.x;
  float am0 = fmaxf((float)(sums[0] * (1.0 / NQ)), 1e-5f);
  float am1 = fmaxf((float)(sums[1] * (1.0 / NP)), 1e-5f);
  if (i == 0) { ams[0] = am0; ams[1] = am1; }
  if (i < NQ) {
    float thr = 0.7f * am0, v = wq[i];
    oq[i] = (v > thr) ? 0x3F80u : ((v < -thr) ? 0xBF80u : 0u);
  } else if (i < NQ + NP) {
    int j = i - NQ;
    float thr = 0.7f * am1, v = wp[j];
    op[j] = (v > thr) ? 0x3F80u : ((v < -thr) ? 0xBF80u : 0u);
  } else {
    int j = i - NQ - NP;                       // 0 .. M_*C_/4-1
    float4 v = ((const float4*)x)[j];
    ushort4 o; o.x = f2b(v.x); o.y = f2b(v.y); o.z = f2b(v.z); o.w = f2b(v.w);
    ((ushort4*)xb)[j] = o;
  }
}

// ---------------- QKV GEMM with fused RoPE/head-split/V-transpose epilogue ----
// dur tracks global_load_lds-staged bytes (~10-13 TB/s chip-wide DMA ceiling;
// MFMA pipe only ~5% busy). 128x192 tile -> staged 320 MB. 4 waves 2M x 2N;
// each N-wave owns interleaved 16-col fragments c = 2j+wn so the RoPE partner
// (col^32 <=> j^1) stays in-wave. Triple-buffer + counted vmcnt(5).

__global__ __launch_bounds__(256) void gemm_qkv(const unsigned short* __restrict__ A,
                                                const unsigned short* __restrict__ W,
                                                const float* __restrict__ scale_ptr,
                                                const float* __restrict__ cosp,
                                                const float* __restrict__ sinp,
                                                unsigned short* __restrict__ Qb,
                                                unsigned short* __restrict__ Kb,
                                                unsigned short* __restrict__ Vtb) {
  const int K = C_;
  __shared__ __attribute__((aligned(16))) unsigned short As[3][128 * 32];
  __shared__ __attribute__((aligned(16))) unsigned short Ws[3][192 * 32];
  const int tid = threadIdx.x, lane = tid & 63, wv = tid >> 6;
  const int m = lane & 15, g = lane >> 4;
  const int m0 = blockIdx.y * 128, n0 = blockIdx.x * 192;
  const int wm = (wv >> 1) * 64, wn = wv & 1;

  const int srow16 = lane >> 2;            // 0..15
  const int skoff = (lane & 3) * 8;
  const unsigned short* ga0 = A + (size_t)(m0 + wv * 32 + srow16) * K + skoff;
  const unsigned short* ga1 = A + (size_t)(m0 + wv * 32 + 16 + srow16) * K + skoff;
  const unsigned short* gw0 = W + (size_t)(n0 + (wv + 0) * 16 + srow16) * K + skoff;
  const unsigned short* gw1 = W + (size_t)(n0 + (wv + 4) * 16 + srow16) * K + skoff;
  const unsigned short* gw2 = W + (size_t)(n0 + (wv + 8) * 16 + srow16) * K + skoff;
  const int oA0 = (wv * 32) * 32;
  const int oA1 = (wv * 32 + 16) * 32;
  const int oW0 = ((wv + 0) * 16) * 32;
  const int oW1 = ((wv + 4) * 16) * 32;
  const int oW2 = ((wv + 8) * 16) * 32;

  floatx4 acc[4][6] = {};

#define QSTAGE(T) do {                                                    \
    gll16(ga0, &As[T][oA0]); gll16(ga1, &As[T][oA1]);                     \
    gll16(gw0, &Ws[T][oW0]); gll16(gw1, &Ws[T][oW1]);                     \
    gll16(gw2, &Ws[T][oW2]);                                              \
    ga0 += 32; ga1 += 32; gw0 += 32; gw1 += 32; gw2 += 32;                \
  } while (0)

#define QCOMP(T) do {                                                     \
    short8 af[4], wf[6];                                                  \
    _Pragma("unroll")                                                     \
    for (int r = 0; r < 4; r++)                                           \
      af[r] = *(const short8*)&As[T][(wm + r * 16 + m) * 32 + g * 8];     \
    _Pragma("unroll")                                                     \
    for (int j = 0; j < 6; j++)                                           \
      wf[j] = *(const short8*)&Ws[T][((2 * j + wn) * 16 + m) * 32 + g * 8]; \
    _Pragma("unroll")                                                     \
    for (int r = 0; r < 4; r++)                                           \
      _Pragma("unroll")                                                   \
      for (int j = 0; j < 6; j++)                                         \
        acc[r][j] = __builtin_amdgcn_mfma_f32_16x16x32_bf16(af[r], wf[j], acc[r][j], 0, 0, 0); \
  } while (0)

  QSTAGE(0);
  QSTAGE(1);
  SYNCV(5);
  for (int tt = 0; tt < 10; ++tt) {
    QSTAGE(2); QCOMP(0); SYNCV(5);
    QSTAGE(0); QCOMP(1); SYNCV(5);
    QSTAGE(1); QCOMP(2); SYNCV(5);
  }
  QCOMP(0); SYNCV(0);
  QCOMP(1);
#undef QSTAGE
#undef QCOMP

  const float am = *scale_ptr;
  #pragma unroll
  for (int j = 0; j < 6; j++) {
    const int colb = n0 + (2 * j + wn) * 16;   // 16-aligned -> uniform per frag
    const int sect = colb >> 10;               // 0=q,1=k,2=v
    const int h = (colb >> 6) & 15;
    const int pb = colb & 63;
    const int p = pb + m;
    if (sect < 2) {
      unsigned short* dst = sect ? Kb : Qb;
      const float sc = sect ? am : am * 0.18033688011112042f;  // am*0.125*log2e
      const bool hi = (pb & 32) != 0;
      #pragma unroll
      for (int r = 0; r < 4; r++)
        #pragma unroll
        for (int i = 0; i < 4; i++) {
          int row = m0 + wm + r * 16 + g * 4 + i;
          int t = row & (T_ - 1), b = row >> 11;
          float cv = cosp[t * 64 + p], sv = sinp[t * 64 + p];
          float a = acc[r][j][i], pt = acc[r][j ^ 1][i];
          float val = hi ? (a * cv + pt * sv) : (a * cv - pt * sv);
          dst[((size_t)(b * H_ + h) * T_ + t) * 64 + p] = f2b(val * sc);
        }
    } else {
      #pragma unroll
      for (int r = 0; r < 4; r++)
        #pragma unroll
        for (int i = 0; i < 4; i++) {
          int row = m0 + wm + r * 16 + g * 4 + i;
          int t = row & (T_ - 1), b = row >> 11;
          size_t hbase = (size_t)(b * H_ + h) * 64 * T_;
          Vtb[hbase + (size_t)p * T_ + t] = f2b(acc[r][j][i] * am);
        }
    }
  }
}

// ---------------- proj GEMM: out[M,N] = (A @ W^T) * scale, fp32 out ----------
// 128x128 tile -> 256 blocks = 1/CU, staged 128 MB. Triple-buffer vmcnt(4).

__global__ __launch_bounds__(256) void gemm_proj(const unsigned short* __restrict__ A,
                                                 const unsigned short* __restrict__ W,
                                                 const float* __restrict__ scale_ptr,
                                                 float* __restrict__ Cout) {
  const int K = C_, N = C_;
  __shared__ __attribute__((aligned(16))) unsigned short As[3][128 * 32];
  __shared__ __attribute__((aligned(16))) unsigned short Ws[3][128 * 32];
  const int tid = threadIdx.x, lane = tid & 63, wv = tid >> 6;
  const int m = lane & 15, g = lane >> 4;
  const int m0 = blockIdx.y * 128, n0 = blockIdx.x * 128;
  const int wm = (wv >> 1) * 64, wn = (wv & 1) * 64;

  const int srow16 = lane >> 2;
  const int skoff = (lane & 3) * 8;
  const unsigned short* ga0 = A + (size_t)(m0 + wv * 32 + srow16) * K + skoff;
  const unsigned short* ga1 = A + (size_t)(m0 + wv * 32 + 16 + srow16) * K + skoff;
  const unsigned short* gw0 = W + (size_t)(n0 + wv * 32 + srow16) * K + skoff;
  const unsigned short* gw1 = W + (size_t)(n0 + wv * 32 + 16 + srow16) * K + skoff;
  const int o0 = (wv * 32) * 32;
  const int o1 = (wv * 32 + 16) * 32;

  floatx4 acc[4][4] = {};

#define PSTAGE(T) do {                                                    \
    gll16(ga0, &As[T][o0]); gll16(ga1, &As[T][o1]);                       \
    gll16(gw0, &Ws[T][o0]); gll16(gw1, &Ws[T][o1]);                       \
    ga0 += 32; ga1 += 32; gw0 += 32; gw1 += 32;                           \
  } while (0)

#define PCOMP(T) do {                                                     \
    short8 af[4], wf[4];                                                  \
    _Pragma("unroll")                                                     \
    for (int r = 0; r < 4; r++)                                           \
      af[r] = *(const short8*)&As[T][(wm + r * 16 + m) * 32 + g * 8];     \
    _Pragma("unroll")                                                     \
    for (int c = 0; c < 4; c++)                                           \
      wf[c] = *(const short8*)&Ws[T][(wn + c * 16 + m) * 32 + g * 8];     \
    _Pragma("unroll")                                                     \
    for (int r = 0; r < 4; r++)                                           \
      _Pragma("unroll")                                                   \
      for (int c = 0; c < 4; c++)                                         \
        acc[r][c] = __builtin_amdgcn_mfma_f32_16x16x32_bf16(af[r], wf[c], acc[r][c], 0, 0, 0); \
  } while (0)

  PSTAGE(0);
  PSTAGE(1);
  SYNCV(4);
  for (int tt = 0; tt < 10; ++tt) {
    PSTAGE(2); PCOMP(0); SYNCV(4);
    PSTAGE(0); PCOMP(1); SYNCV(4);
    PSTAGE(1); PCOMP(2); SYNCV(4);
  }
  PCOMP(0); SYNCV(0);
  PCOMP(1);
#undef PSTAGE
#undef PCOMP

  const float scale = *scale_ptr;
  #pragma unroll
  for (int r = 0; r < 4; r++)
    #pragma unroll
    for (int c = 0; c < 4; c++)
      #pragma unroll
      for (int i = 0; i < 4; i++) {
        int row = m0 + wm + r * 16 + g * 4 + i;
        int col = n0 + wn + c * 16 + m;
        Cout[(size_t)row * N + col] = acc[r][c][i] * scale;
      }
}

// ---------------- MFMA flash attention, m=0 softmax, BARRIER-FREE ------------
// R6 lesson: flash is serial-chain/barrier-bound, not DMA-bound (45us = 6TB/s
// staged, under the ~10TB/s ceiling). K/V per XCD (4 bh) = 4MB = L2-resident,
// so LDS staging is pure overhead (guide mistake #7). New structure: zero
// block barriers; each wave loads its K/V fragments directly global->VGPR
// (16 b128/iter, 64B lines fully consumed, L2-served) and runs its 16-q strip
// independently. m=0 softmax => pure sum over k-tiles, no inter-wave coupling.
// Only per-wave Plds round-trip remains (compiler lgkmcnt, no barrier).
// 1024 blocks (32 strips x 32 bh), LPT + XCD-grouped bh as before.

__global__ __launch_bounds__(256) void flash_mfma(const unsigned short* __restrict__ Qb,
                                                  const unsigned short* __restrict__ Kb,
                                                  const unsigned short* __restrict__ Vtb,
                                                  unsigned short* __restrict__ Y) {
  __shared__ __align__(16) unsigned short Plds[4][16][72];
  const int lane = threadIdx.x & 63;
  const int wv = threadIdx.x >> 6;
  const int m = lane & 15, g = lane >> 4;
  const int gid = blockIdx.x;
  const int xcd = gid & 7, j = gid >> 3;    // j: 0..127
  const int bh = xcd * 4 + (j & 3);
  const int s = 31 - (j >> 2);              // long strips dispatched first
  const int b = bh >> 4, h = bh & 15;
  const size_t hb = (size_t)bh * T_ * 64;

  const int ntiles = s + 1;
  const int qbase = s * 64 + wv * 16;
  const int q_glob = qbase + m;

  const unsigned short* qp = Qb + hb + (size_t)(qbase + m) * 64 + g * 8;
  short8 qf0 = *(const short8*)qp;
  short8 qf1 = *(const short8*)(qp + 32);

  // per-lane fragment pointers: K row m (+mt*16), cols g*8 / 32+g*8;
  // V row d=m (+nt*16), col t = kt*64 + g*8 / +32   (Vtb is [bh][d][T])
  const unsigned short* kp = Kb + hb + m * 64 + g * 8;
  const unsigned short* vp = Vtb + hb + (size_t)m * T_ + g * 8;

  short8 ones;
  #pragma unroll
  for (int i = 0; i < 8; i++) ones[i] = (short)0x3F80;  // bf16 1.0

  floatx4 O[4] = {};
  floatx4 accl = {};

  for (int kt = 0; kt < ntiles; kt++) {
    const unsigned short* kb_ = kp + (size_t)kt * 64 * 64;
    const unsigned short* vb_ = vp + kt * 64;
    short8 kf[4][2], vf[4][2];
    #pragma unroll
    for (int mt = 0; mt < 4; mt++) {
      kf[mt][0] = *(const short8*)(kb_ + mt * 16 * 64);
      kf[mt][1] = *(const short8*)(kb_ + mt * 16 * 64 + 32);
    }
    #pragma unroll
    for (int nt = 0; nt < 4; nt++) {
      vf[nt][0] = *(const short8*)(vb_ + (size_t)nt * 16 * T_);
      vf[nt][1] = *(const short8*)(vb_ + (size_t)nt * 16 * T_ + 32);
    }
    // S^T = K * Q^T
    floatx4 S[4];
    __builtin_amdgcn_s_setprio(1);
    #pragma unroll
    for (int mt = 0; mt < 4; mt++) {
      floatx4 sv = {};
      sv = __builtin_amdgcn_mfma_f32_16x16x32_bf16(kf[mt][0], qf0, sv, 0, 0, 0);
      sv = __builtin_amdgcn_mfma_f32_16x16x32_bf16(kf[mt][1], qf1, sv, 0, 0, 0);
      S[mt] = sv;
    }
    __builtin_amdgcn_s_setprio(0);
    if (kt + 1 < ntiles) {                   // fully unmasked tile
      #pragma unroll
      for (int mt = 0; mt < 4; mt++) {
        uint2 w;
        w.x = pk2(exp2f(S[mt][0]), exp2f(S[mt][1]));
        w.y = pk2(exp2f(S[mt][2]), exp2f(S[mt][3]));
        *(uint2*)&Plds[wv][m][mt * 16 + g * 4] = w;
      }
    } else {                                 // diagonal tile: causal mask
      #pragma unroll
      for (int mt = 0; mt < 4; mt++) {
        float e[4];
        #pragma unroll
        for (int r = 0; r < 4; r++) {
          int kg = kt * 64 + mt * 16 + g * 4 + r;
          e[r] = (kg <= q_glob) ? exp2f(S[mt][r]) : 0.f;
        }
        uint2 w;
        w.x = pk2(e[0], e[1]);
        w.y = pk2(e[2], e[3]);
        *(uint2*)&Plds[wv][m][mt * 16 + g * 4] = w;
      }
    }
    short8 pa0 = *(const short8*)&Plds[wv][m][g * 8];
    short8 pa1 = *(const short8*)&Plds[wv][m][32 + g * 8];
    __builtin_amdgcn_s_setprio(1);
    #pragma unroll
    for (int nt = 0; nt < 4; nt++) {
      O[nt] = __builtin_amdgcn_mfma_f32_16x16x32_bf16(pa0, vf[nt][0], O[nt], 0, 0, 0);
      O[nt] = __builtin_amdgcn_mfma_f32_16x16x32_bf16(pa1, vf[nt][1], O[nt], 0, 0, 0);
    }
    accl = __builtin_amdgcn_mfma_f32_16x16x32_bf16(pa0, ones, accl, 0, 0, 0);
    accl = __builtin_amdgcn_mfma_f32_16x16x32_bf16(pa1, ones, accl, 0, 0, 0);
    __builtin_amdgcn_s_setprio(0);
  }

  // accl[r] = l(q = qbase + g*4 + r) -- no cross-lane reduction needed
  float li[4];
  #pragma unroll
  for (int r = 0; r < 4; r++) li[r] = 1.0f / accl[r];
  #pragma unroll
  for (int nt = 0; nt < 4; nt++)
    #pragma unroll
    for (int r = 0; r < 4; r++) {
      int trow = qbase + g * 4 + r;
      int col = h * 64 + nt * 16 + m;
      Y[(size_t)(b * T_ + trow) * C_ + col] = f2b(O[nt][r] * li[r]);
    }
}

// ---------------- launch ----------------

extern "C" void kernel_launch(void* const* d_in, const int* in_sizes, int n_in,
                              void* d_out, int out_size, void* d_ws, size_t ws_size,
                              hipStream_t stream) {
  (void)in_sizes; (void)n_in; (void)out_size; (void)ws_size;
  const float* x      = (const float*)d_in[0];
  const float* cosp   = (const float*)d_in[1];
  const float* sinp   = (const float*)d_in[2];
  const float* w_qkv  = (const float*)d_in[3];
  const float* w_proj = (const float*)d_in[4];
  float* out = (float*)d_out;

  char* ws = (char*)d_ws;
  double* sums = (double*)ws;                       // 16 B
  float*  ams  = (float*)(ws + 16);                 // 8 B
  unsigned short* wqkv_b  = (unsigned short*)(ws + 256);            // 6 MB
  unsigned short* wproj_b = wqkv_b + (size_t)N3C * C_;              // 2 MB
  unsigned short* xb      = wproj_b + (size_t)C_ * C_;              // 8 MB
  unsigned short* Qb      = xb + (size_t)M_ * C_;                   // 8 MB
  unsigned short* Kb      = Qb + (size_t)B_ * H_ * T_ * D_;         // 8 MB
  unsigned short* Vtb     = Kb + (size_t)B_ * H_ * T_ * D_;         // 8 MB
  unsigned short* yb      = Vtb + (size_t)B_ * H_ * T_ * D_;        // 8 MB

  hipMemsetAsync(sums, 0, 16, stream);
  abs_sum2<<<dim3(256, 2), 256, 0, stream>>>(w_qkv, w_proj, sums);
  tern_cvt<<<(4 * C_ * C_ + M_ * C_ / 4) / 256, 256, 0, stream>>>(w_qkv, w_proj, x,
                                                                  wqkv_b, wproj_b, xb,
                                                                  sums, ams);
  gemm_qkv<<<dim3(N3C / 192, M_ / 128), 256, 0, stream>>>(xb, wqkv_b, ams + 0,
                                                          cosp, sinp, Qb, Kb, Vtb);
  flash_mfma<<<1024, 256, 0, stream>>>(Qb, Kb, Vtb, yb);
  gemm_proj<<<dim3(C_ / 128, M_ / 128), 256, 0, stream>>>(yb, wproj_b, ams + 1, out);
}

// Round 8
// 194.741 us; speedup vs baseline: 1.4779x; 1.4779x over previous
//
#include <hip/hip_runtime.h>
#include <hip/hip_bf16.h>

// Problem constants: B=2, T=2048, C=1024, H=16, D=64
#define B_ 2
#define T_ 2048
#define C_ 1024
#define H_ 16
#define D_ 64
#define M_ 4096
#define N3C 3072

using short8  = __attribute__((ext_vector_type(8))) short;
using floatx4 = __attribute__((ext_vector_type(4))) float;
typedef unsigned int u32;

__device__ __forceinline__ unsigned short f2b(float f) {
  __hip_bfloat16 h = __float2bfloat16(f);
  return *reinterpret_cast<unsigned short*>(&h);
}
__device__ __forceinline__ float b2f(unsigned short u) {
  union { unsigned int i; float f; } x; x.i = ((unsigned int)u) << 16; return x.f;
}
__device__ __forceinline__ u32 pk2(float a, float b) {   // packed bf16x2
  float2 t; t.x = a; t.y = b;
  __hip_bfloat162 p = __float22bfloat162_rn(t);
  return *reinterpret_cast<u32*>(&p);
}

// raw v_exp_f32 (2^x) without the OCML denorm/range wrapper
#if __has_builtin(__builtin_amdgcn_exp2f)
__device__ __forceinline__ float ex2(float x) { return __builtin_amdgcn_exp2f(x); }
#else
__device__ __forceinline__ float ex2(float x) { return exp2f(x); }
#endif

// async global->LDS, 16B per lane; LDS dest = wave-uniform base + lane*16
__device__ __forceinline__ void gll16(const void* g, void* l) {
  __builtin_amdgcn_global_load_lds((const __attribute__((address_space(1))) u32*)g,
                                   (__attribute__((address_space(3))) u32*)l, 16, 0, 0);
}

// counted-vmcnt barrier: wait until at most N vmem ops outstanding, then
// block-barrier. asm memory clobbers sandwich the barrier so the compiler
// cannot hoist/sink LDS accesses across it.
#define SYNCV(N) do {                                                   \
    asm volatile("s_waitcnt vmcnt(" #N ")" ::: "memory");               \
    __builtin_amdgcn_s_barrier();                                       \
    asm volatile("" ::: "memory");                                      \
  } while (0)

// ---------------- ternarization ----------------

// both tensors in one launch; per-block LDS reduce -> 1 atomic/block
__global__ void abs_sum2(const float* __restrict__ wq, const float* __restrict__ wp,
                         double* __restrict__ sums) {
  __shared__ double red[4];
  const float* w = blockIdx.y ? wp : wq;
  const int n4 = blockIdx.y ? (C_ * C_ / 4) : (3 * C_ * C_ / 4);
  int stride = gridDim.x * blockDim.x;
  double s = 0.0;
  for (int i = blockIdx.x * blockDim.x + threadIdx.x; i < n4; i += stride) {
    float4 v = ((const float4*)w)[i];
    s += (double)fabsf(v.x) + (double)fabsf(v.y) + (double)fabsf(v.z) + (double)fabsf(v.w);
  }
  #pragma unroll
  for (int off = 32; off > 0; off >>= 1)
    s += __shfl_down(s, off, 64);
  if ((threadIdx.x & 63) == 0) red[threadIdx.x >> 6] = s;
  __syncthreads();
  if (threadIdx.x == 0) atomicAdd(sums + blockIdx.y, (red[0] + red[1]) + (red[2] + red[3]));
}

// ternarize both weight tensors (exact {-1,0,+1} bf16) + cvt x->bf16, one launch
__global__ void tern_cvt(const float* __restrict__ wq, const float* __restrict__ wp,
                         const float* __restrict__ x,
                         unsigned short* __restrict__ oq, unsigned short* __restrict__ op,
                         unsigned short* __restrict__ xb,
                         const double* __restrict__ sums, float* __restrict__ ams) {
  const int NQ = 3 * C_ * C_;
  const int NP = C_ * C_;
  int i = blockIdx.x * blockDim.x + threadIdx.x;
  float am0 = fmaxf((float)(sums[0] * (1.0 / NQ)), 1e-5f);
  float am1 = fmaxf((float)(sums[1] * (1.0 / NP)), 1e-5f);
  if (i == 0) { ams[0] = am0; ams[1] = am1; }
  if (i < NQ) {
    float thr = 0.7f * am0, v = wq[i];
    oq[i] = (v > thr) ? 0x3F80u : ((v < -thr) ? 0xBF80u : 0u);
  } else if (i < NQ + NP) {
    int j = i - NQ;
    float thr = 0.7f * am1, v = wp[j];
    op[j] = (v > thr) ? 0x3F80u : ((v < -thr) ? 0xBF80u : 0u);
  } else {
    int j = i - NQ - NP;                       // 0 .. M_*C_/4-1
    float4 v = ((const float4*)x)[j];
    ushort4 o; o.x = f2b(v.x); o.y = f2b(v.y); o.z = f2b(v.z); o.w = f2b(v.w);
    ((ushort4*)xb)[j] = o;
  }
}

// ---------------- QKV GEMM with fused RoPE/head-split/V-transpose epilogue ----
// dur tracks global_load_lds-staged bytes (~10-13 TB/s chip-wide DMA ceiling;
// MFMA pipe only ~5% busy). 128x192 tile -> staged 320 MB. 4 waves 2M x 2N;
// each N-wave owns interleaved 16-col fragments c = 2j+wn so the RoPE partner
// (col^32 <=> j^1) stays in-wave. Triple-buffer + counted vmcnt(5).

__global__ __launch_bounds__(256) void gemm_qkv(const unsigned short* __restrict__ A,
                                                const unsigned short* __restrict__ W,
                                                const float* __restrict__ scale_ptr,
                                                const float* __restrict__ cosp,
                                                const float* __restrict__ sinp,
                                                unsigned short* __restrict__ Qb,
                                                unsigned short* __restrict__ Kb,
                                                unsigned short* __restrict__ Vtb) {
  const int K = C_;
  __shared__ __attribute__((aligned(16))) unsigned short As[3][128 * 32];
  __shared__ __attribute__((aligned(16))) unsigned short Ws[3][192 * 32];
  const int tid = threadIdx.x, lane = tid & 63, wv = tid >> 6;
  const int m = lane & 15, g = lane >> 4;
  const int m0 = blockIdx.y * 128, n0 = blockIdx.x * 192;
  const int wm = (wv >> 1) * 64, wn = wv & 1;

  const int srow16 = lane >> 2;            // 0..15
  const int skoff = (lane & 3) * 8;
  const unsigned short* ga0 = A + (size_t)(m0 + wv * 32 + srow16) * K + skoff;
  const unsigned short* ga1 = A + (size_t)(m0 + wv * 32 + 16 + srow16) * K + skoff;
  const unsigned short* gw0 = W + (size_t)(n0 + (wv + 0) * 16 + srow16) * K + skoff;
  const unsigned short* gw1 = W + (size_t)(n0 + (wv + 4) * 16 + srow16) * K + skoff;
  const unsigned short* gw2 = W + (size_t)(n0 + (wv + 8) * 16 + srow16) * K + skoff;
  const int oA0 = (wv * 32) * 32;
  const int oA1 = (wv * 32 + 16) * 32;
  const int oW0 = ((wv + 0) * 16) * 32;
  const int oW1 = ((wv + 4) * 16) * 32;
  const int oW2 = ((wv + 8) * 16) * 32;

  floatx4 acc[4][6] = {};

#define QSTAGE(T) do {                                                    \
    gll16(ga0, &As[T][oA0]); gll16(ga1, &As[T][oA1]);                     \
    gll16(gw0, &Ws[T][oW0]); gll16(gw1, &Ws[T][oW1]);                     \
    gll16(gw2, &Ws[T][oW2]);                                              \
    ga0 += 32; ga1 += 32; gw0 += 32; gw1 += 32; gw2 += 32;                \
  } while (0)

#define QCOMP(T) do {                                                     \
    short8 af[4], wf[6];                                                  \
    _Pragma("unroll")                                                     \
    for (int r = 0; r < 4; r++)                                           \
      af[r] = *(const short8*)&As[T][(wm + r * 16 + m) * 32 + g * 8];     \
    _Pragma("unroll")                                                     \
    for (int j = 0; j < 6; j++)                                           \
      wf[j] = *(const short8*)&Ws[T][((2 * j + wn) * 16 + m) * 32 + g * 8]; \
    _Pragma("unroll")                                                     \
    for (int r = 0; r < 4; r++)                                           \
      _Pragma("unroll")                                                   \
      for (int j = 0; j < 6; j++)                                         \
        acc[r][j] = __builtin_amdgcn_mfma_f32_16x16x32_bf16(af[r], wf[j], acc[r][j], 0, 0, 0); \
  } while (0)

  QSTAGE(0);
  QSTAGE(1);
  SYNCV(5);
  for (int tt = 0; tt < 10; ++tt) {
    QSTAGE(2); QCOMP(0); SYNCV(5);
    QSTAGE(0); QCOMP(1); SYNCV(5);
    QSTAGE(1); QCOMP(2); SYNCV(5);
  }
  QCOMP(0); SYNCV(0);
  QCOMP(1);
#undef QSTAGE
#undef QCOMP

  const float am = *scale_ptr;
  #pragma unroll
  for (int j = 0; j < 6; j++) {
    const int colb = n0 + (2 * j + wn) * 16;   // 16-aligned -> uniform per frag
    const int sect = colb >> 10;               // 0=q,1=k,2=v
    const int h = (colb >> 6) & 15;
    const int pb = colb & 63;
    const int p = pb + m;
    if (sect < 2) {
      unsigned short* dst = sect ? Kb : Qb;
      const float sc = sect ? am : am * 0.18033688011112042f;  // am*0.125*log2e
      const bool hi = (pb & 32) != 0;
      #pragma unroll
      for (int r = 0; r < 4; r++)
        #pragma unroll
        for (int i = 0; i < 4; i++) {
          int row = m0 + wm + r * 16 + g * 4 + i;
          int t = row & (T_ - 1), b = row >> 11;
          float cv = cosp[t * 64 + p], sv = sinp[t * 64 + p];
          float a = acc[r][j][i], pt = acc[r][j ^ 1][i];
          float val = hi ? (a * cv + pt * sv) : (a * cv - pt * sv);
          dst[((size_t)(b * H_ + h) * T_ + t) * 64 + p] = f2b(val * sc);
        }
    } else {
      #pragma unroll
      for (int r = 0; r < 4; r++)
        #pragma unroll
        for (int i = 0; i < 4; i++) {
          int row = m0 + wm + r * 16 + g * 4 + i;
          int t = row & (T_ - 1), b = row >> 11;
          size_t hbase = (size_t)(b * H_ + h) * 64 * T_;
          Vtb[hbase + (size_t)p * T_ + t] = f2b(acc[r][j][i] * am);
        }
    }
  }
}

// ---------------- proj GEMM: out[M,N] = (A @ W^T) * scale, fp32 out ----------
// 128x128 tile -> 256 blocks = 1/CU, staged 128 MB. Triple-buffer vmcnt(4).

__global__ __launch_bounds__(256) void gemm_proj(const unsigned short* __restrict__ A,
                                                 const unsigned short* __restrict__ W,
                                                 const float* __restrict__ scale_ptr,
                                                 float* __restrict__ Cout) {
  const int K = C_, N = C_;
  __shared__ __attribute__((aligned(16))) unsigned short As[3][128 * 32];
  __shared__ __attribute__((aligned(16))) unsigned short Ws[3][128 * 32];
  const int tid = threadIdx.x, lane = tid & 63, wv = tid >> 6;
  const int m = lane & 15, g = lane >> 4;
  const int m0 = blockIdx.y * 128, n0 = blockIdx.x * 128;
  const int wm = (wv >> 1) * 64, wn = (wv & 1) * 64;

  const int srow16 = lane >> 2;
  const int skoff = (lane & 3) * 8;
  const unsigned short* ga0 = A + (size_t)(m0 + wv * 32 + srow16) * K + skoff;
  const unsigned short* ga1 = A + (size_t)(m0 + wv * 32 + 16 + srow16) * K + skoff;
  const unsigned short* gw0 = W + (size_t)(n0 + wv * 32 + srow16) * K + skoff;
  const unsigned short* gw1 = W + (size_t)(n0 + wv * 32 + 16 + srow16) * K + skoff;
  const int o0 = (wv * 32) * 32;
  const int o1 = (wv * 32 + 16) * 32;

  floatx4 acc[4][4] = {};

#define PSTAGE(T) do {                                                    \
    gll16(ga0, &As[T][o0]); gll16(ga1, &As[T][o1]);                       \
    gll16(gw0, &Ws[T][o0]); gll16(gw1, &Ws[T][o1]);                       \
    ga0 += 32; ga1 += 32; gw0 += 32; gw1 += 32;                           \
  } while (0)

#define PCOMP(T) do {                                                     \
    short8 af[4], wf[4];                                                  \
    _Pragma("unroll")                                                     \
    for (int r = 0; r < 4; r++)                                           \
      af[r] = *(const short8*)&As[T][(wm + r * 16 + m) * 32 + g * 8];     \
    _Pragma("unroll")                                                     \
    for (int c = 0; c < 4; c++)                                           \
      wf[c] = *(const short8*)&Ws[T][(wn + c * 16 + m) * 32 + g * 8];     \
    _Pragma("unroll")                                                     \
    for (int r = 0; r < 4; r++)                                           \
      _Pragma("unroll")                                                   \
      for (int c = 0; c < 4; c++)                                         \
        acc[r][c] = __builtin_amdgcn_mfma_f32_16x16x32_bf16(af[r], wf[c], acc[r][c], 0, 0, 0); \
  } while (0)

  PSTAGE(0);
  PSTAGE(1);
  SYNCV(4);
  for (int tt = 0; tt < 10; ++tt) {
    PSTAGE(2); PCOMP(0); SYNCV(4);
    PSTAGE(0); PCOMP(1); SYNCV(4);
    PSTAGE(1); PCOMP(2); SYNCV(4);
  }
  PCOMP(0); SYNCV(0);
  PCOMP(1);
#undef PSTAGE
#undef PCOMP

  const float scale = *scale_ptr;
  #pragma unroll
  for (int r = 0; r < 4; r++)
    #pragma unroll
    for (int c = 0; c < 4; c++)
      #pragma unroll
      for (int i = 0; i < 4; i++) {
        int row = m0 + wm + r * 16 + g * 4 + i;
        int col = n0 + wn + c * 16 + m;
        Cout[(size_t)row * N + col] = acc[r][c][i] * scale;
      }
}

// ---------------- MFMA flash attention, m=0 softmax, LDS-staged K/V ----------
// R5 structure restored (proven 45.4us; QBLK=128 and barrier-free both lost:
// LDS staging's value = 4-wave amortization + latency decoupling). 1024 blocks
// (32 strips x 32 bh), LPT + XCD swizzle. Wave owns 16 q; K/V double-buffered
// via gll16; one __syncthreads per k-tile. Changes vs R5: raw v_exp_f32 (ex2)
// instead of OCML exp2f wrapper (VALU was 49% busy, 4x my op-count model ->
// wrapper fixup suspected), and setprio(1) around MFMA clusters (m191).

__global__ __launch_bounds__(256) void flash_mfma(const unsigned short* __restrict__ Qb,
                                                  const unsigned short* __restrict__ Kb,
                                                  const unsigned short* __restrict__ Vtb,
                                                  unsigned short* __restrict__ Y) {
  __shared__ __align__(16) unsigned short Ktile[2][64][64];   // [buf][t][d]
  __shared__ __align__(16) unsigned short Vtile[2][64][64];   // [buf][d][t]
  __shared__ __align__(16) unsigned short Plds[4][16][72];
  const int lane = threadIdx.x & 63;
  const int wv = threadIdx.x >> 6;
  const int m = lane & 15, g = lane >> 4;
  const int gid = blockIdx.x;
  const int xcd = gid & 7, j = gid >> 3;    // j: 0..127
  const int bh = xcd * 4 + (j & 3);
  const int s = 31 - (j >> 2);              // long strips dispatched first
  const int b = bh >> 4, h = bh & 15;
  const size_t hb = (size_t)bh * T_ * 64;
  const unsigned short* Kbh = Kb + hb;
  const unsigned short* Vbh = Vtb + hb;     // [64][T_]
  const int r8 = lane >> 3, cc8 = lane & 7;
  const int gcol = ((cc8 ^ r8) << 3);       // swizzled global chunk

  const int ntiles = s + 1;
  const int qbase = s * 64 + wv * 16;
  const int q_glob = qbase + m;

  const unsigned short* qp = Qb + hb + (size_t)(qbase + m) * 64 + g * 8;
  short8 qf0 = *(const short8*)qp;
  short8 qf1 = *(const short8*)(qp + 32);

  short8 ones;
  #pragma unroll
  for (int i = 0; i < 8; i++) ones[i] = (short)0x3F80;  // bf16 1.0

  floatx4 O[4] = {};
  floatx4 accl = {};

  #pragma unroll
  for (int cc = 0; cc < 2; cc++) {          // stage tile 0 -> buf 0
    int row = wv * 16 + cc * 8;
    gll16(Kbh + (size_t)(row + r8) * 64 + gcol, &Ktile[0][row][0]);
    gll16(Vbh + (size_t)(row + r8) * T_ + gcol, &Vtile[0][row][0]);
  }

  for (int kt = 0; kt < ntiles; kt++) {
    const int buf = kt & 1;
    const int kb = kt * 64;
    __syncthreads();                         // stage(kt) visible
    if (kt + 1 < ntiles) {                   // stream next tile
      const int kb2 = kb + 64;
      #pragma unroll
      for (int cc = 0; cc < 2; cc++) {
        int row = wv * 16 + cc * 8;
        gll16(Kbh + (size_t)(kb2 + row + r8) * 64 + gcol, &Ktile[1 - buf][row][0]);
        gll16(Vbh + (size_t)(row + r8) * T_ + kb2 + gcol, &Vtile[1 - buf][row][0]);
      }
    }
    // S^T = K * Q^T  (swizzled reads: G[r][c] = LDS[r][c ^ (r&7)])
    floatx4 S[4];
    __builtin_amdgcn_s_setprio(1);
    #pragma unroll
    for (int mt = 0; mt < 4; mt++) {
      int row = mt * 16 + m;
      short8 kf0 = *(const short8*)&Ktile[buf][row][(g ^ (m & 7)) << 3];
      short8 kf1 = *(const short8*)&Ktile[buf][row][((g + 4) ^ (m & 7)) << 3];
      floatx4 sv = {};
      sv = __builtin_amdgcn_mfma_f32_16x16x32_bf16(kf0, qf0, sv, 0, 0, 0);
      sv = __builtin_amdgcn_mfma_f32_16x16x32_bf16(kf1, qf1, sv, 0, 0, 0);
      S[mt] = sv;
    }
    __builtin_amdgcn_s_setprio(0);
    if (kt + 1 < ntiles) {                   // fully unmasked tile
      #pragma unroll
      for (int mt = 0; mt < 4; mt++) {
        uint2 w;
        w.x = pk2(ex2(S[mt][0]), ex2(S[mt][1]));
        w.y = pk2(ex2(S[mt][2]), ex2(S[mt][3]));
        *(uint2*)&Plds[wv][m][mt * 16 + g * 4] = w;
      }
    } else {                                 // diagonal tile: causal mask
      #pragma unroll
      for (int mt = 0; mt < 4; mt++) {
        float e[4];
        #pragma unroll
        for (int r = 0; r < 4; r++) {
          int kg = kb + mt * 16 + g * 4 + r;
          e[r] = (kg <= q_glob) ? ex2(S[mt][r]) : 0.f;
        }
        uint2 w;
        w.x = pk2(e[0], e[1]);
        w.y = pk2(e[2], e[3]);
        *(uint2*)&Plds[wv][m][mt * 16 + g * 4] = w;
      }
    }
    short8 pa0 = *(const short8*)&Plds[wv][m][g * 8];
    short8 pa1 = *(const short8*)&Plds[wv][m][32 + g * 8];
    __builtin_amdgcn_s_setprio(1);
    #pragma unroll
    for (int nt = 0; nt < 4; nt++) {
      int row = nt * 16 + m;
      short8 v0 = *(const short8*)&Vtile[buf][row][(g ^ (m & 7)) << 3];
      short8 v1 = *(const short8*)&Vtile[buf][row][((g + 4) ^ (m & 7)) << 3];
      O[nt] = __builtin_amdgcn_mfma_f32_16x16x32_bf16(pa0, v0, O[nt], 0, 0, 0);
      O[nt] = __builtin_amdgcn_mfma_f32_16x16x32_bf16(pa1, v1, O[nt], 0, 0, 0);
    }
    accl = __builtin_amdgcn_mfma_f32_16x16x32_bf16(pa0, ones, accl, 0, 0, 0);
    accl = __builtin_amdgcn_mfma_f32_16x16x32_bf16(pa1, ones, accl, 0, 0, 0);
    __builtin_amdgcn_s_setprio(0);
  }

  // accl[r] = l(q = qbase + g*4 + r) -- no cross-lane reduction needed
  float li[4];
  #pragma unroll
  for (int r = 0; r < 4; r++) li[r] = 1.0f / accl[r];
  #pragma unroll
  for (int nt = 0; nt < 4; nt++)
    #pragma unroll
    for (int r = 0; r < 4; r++) {
      int trow = qbase + g * 4 + r;
      int col = h * 64 + nt * 16 + m;
      Y[(size_t)(b * T_ + trow) * C_ + col] = f2b(O[nt][r] * li[r]);
    }
}

// ---------------- launch ----------------

extern "C" void kernel_launch(void* const* d_in, const int* in_sizes, int n_in,
                              void* d_out, int out_size, void* d_ws, size_t ws_size,
                              hipStream_t stream) {
  (void)in_sizes; (void)n_in; (void)out_size; (void)ws_size;
  const float* x      = (const float*)d_in[0];
  const float* cosp   = (const float*)d_in[1];
  const float* sinp   = (const float*)d_in[2];
  const float* w_qkv  = (const float*)d_in[3];
  const float* w_proj = (const float*)d_in[4];
  float* out = (float*)d_out;

  char* ws = (char*)d_ws;
  double* sums = (double*)ws;                       // 16 B
  float*  ams  = (float*)(ws + 16);                 // 8 B
  unsigned short* wqkv_b  = (unsigned short*)(ws + 256);            // 6 MB
  unsigned short* wproj_b = wqkv_b + (size_t)N3C * C_;              // 2 MB
  unsigned short* xb      = wproj_b + (size_t)C_ * C_;              // 8 MB
  unsigned short* Qb      = xb + (size_t)M_ * C_;                   // 8 MB
  unsigned short* Kb      = Qb + (size_t)B_ * H_ * T_ * D_;         // 8 MB
  unsigned short* Vtb     = Kb + (size_t)B_ * H_ * T_ * D_;         // 8 MB
  unsigned short* yb      = Vtb + (size_t)B_ * H_ * T_ * D_;        // 8 MB

  hipMemsetAsync(sums, 0, 16, stream);
  abs_sum2<<<dim3(256, 2), 256, 0, stream>>>(w_qkv, w_proj, sums);
  tern_cvt<<<(4 * C_ * C_ + M_ * C_ / 4) / 256, 256, 0, stream>>>(w_qkv, w_proj, x,
                                                                  wqkv_b, wproj_b, xb,
                                                                  sums, ams);
  gemm_qkv<<<dim3(N3C / 192, M_ / 128), 256, 0, stream>>>(xb, wqkv_b, ams + 0,
                                                          cosp, sinp, Qb, Kb, Vtb);
  flash_mfma<<<1024, 256, 0, stream>>>(Qb, Kb, Vtb, yb);
  gemm_proj<<<dim3(C_ / 128, M_ / 128), 256, 0, stream>>>(yb, wproj_b, ams + 1, out);
}